// Round 6
// baseline (1554.685 us; speedup 1.0000x reference)
//
#include <hip/hip_runtime.h>
#include <stdint.h>

#define B_   32
#define C_   256
#define HW_  4096
#define N_   131072   // B*H*W rows
#define K_   1024     // codebook size
#define GAP_THR 1.25e-4f

typedef __attribute__((ext_vector_type(8))) short bf16x8;
typedef __attribute__((ext_vector_type(4))) float f32x4;
typedef unsigned long long u64;

__device__ __forceinline__ unsigned short f2bf(float f) {
    unsigned int x = __float_as_uint(f);
    return (unsigned short)((x + 0x7FFFu + ((x >> 16) & 1u)) >> 16);   // RNE
}
__device__ __forceinline__ float bf2f(unsigned short h) {
    return __uint_as_float(((unsigned int)h) << 16);
}
__device__ __forceinline__ u64 shfl_xor64(u64 v, int m) {
    int lo = __shfl_xor((int)(v & 0xFFFFFFFFull), m, 64);
    int hi = __shfl_xor((int)(v >> 32), m, 64);
    return ((u64)(unsigned int)hi << 32) | (unsigned int)lo;
}
__device__ __forceinline__ float unpack_d(u64 p) {
    uint32_t u = (uint32_t)(p >> 10);
    uint32_t b = (u & 0x80000000u) ? (u ^ 0x80000000u) : ~u;
    return __uint_as_float(b);
}

#define GLD16(g, l) __builtin_amdgcn_global_load_lds((const __attribute__((address_space(1))) void*)(g), \
                        (__attribute__((address_space(3))) void*)(l), 16, 0, 0)

// ---------------- ||e_k||^2, replicating numpy pairwise_sum(256) ----------------
__global__ void ee_kernel(const float* __restrict__ emb, float* __restrict__ ee) {
#pragma clang fp contract(off)
    int k = blockIdx.x * blockDim.x + threadIdx.x;
    if (k >= K_) return;
    const float* e = emb + (size_t)k * C_;
    float res = 0.f;
    for (int h = 0; h < 2; ++h) {
        float r[8];
        #pragma unroll
        for (int j = 0; j < 8; ++j) { float v = e[h*128 + j]; r[j] = v * v; }
        for (int i = 8; i < 128; i += 8) {
            #pragma unroll
            for (int j = 0; j < 8; ++j) { float v = e[h*128 + i + j]; r[j] += v * v; }
        }
        float s = ((r[0] + r[1]) + (r[2] + r[3])) + ((r[4] + r[5]) + (r[6] + r[7]));
        res += s;
    }
    ee[k] = res;
}

// ---------------- emb -> bf16 hi/lo split, [k][c] layout ----------------
__global__ void esplit_kernel(const float* __restrict__ emb,
                              unsigned short* __restrict__ eh, unsigned short* __restrict__ el) {
    int t = blockIdx.x * 256 + threadIdx.x;            // 32768 threads
    int k = t >> 5, c8 = (t & 31) * 8;
    const float* src = emb + (size_t)k * C_ + c8;
    unsigned short hb[8], lb[8];
    #pragma unroll
    for (int i = 0; i < 8; ++i) {
        float f = src[i];
        unsigned short h = f2bf(f);
        hb[i] = h; lb[i] = f2bf(f - bf2f(h));
    }
    size_t off = (size_t)k * C_ + c8;
    *(uint4*)&eh[off] = *(uint4*)hb;
    *(uint4*)&el[off] = *(uint4*)lb;
}

// ---------------- z -> bf16 hi/lo split, TRANSPOSED to [n][c] layout ----------------
__global__ void zsplit_kernel(const float* __restrict__ z,
                              unsigned short* __restrict__ zh, unsigned short* __restrict__ zl) {
    __shared__ float t[64][65];
    int blk = blockIdx.x;
    int b = blk >> 8, ct = (blk >> 6) & 3, ht = blk & 63;
    int tid = threadIdx.x;
    int hw = tid & 63, c0 = tid >> 6;
    const float* src = z + ((size_t)b * C_ + ct * 64) * HW_ + ht * 64;
    #pragma unroll
    for (int k = 0; k < 16; ++k) {
        int c = k * 4 + c0;
        t[c][hw] = src[(size_t)c * HW_ + hw];
    }
    __syncthreads();
    int hw2 = tid >> 2, cs = (tid & 3) * 16;
    size_t off = ((size_t)b * HW_ + ht * 64 + hw2) * C_ + ct * 64 + cs;
    unsigned short hb[16], lb[16];
    #pragma unroll
    for (int i = 0; i < 16; ++i) {
        float f = t[cs + i][hw2];
        unsigned short h = f2bf(f);
        hb[i] = h; lb[i] = f2bf(f - bf2f(h));
    }
    *(uint4*)&zh[off]     = *(uint4*)&hb[0];
    *(uint4*)&zh[off + 8] = *(uint4*)&hb[8];
    *(uint4*)&zl[off]     = *(uint4*)&lb[0];
    *(uint4*)&zl[off + 8] = *(uint4*)&lb[8];
}

// ---------------- MFMA approx-distance + per-row top-2 (full-precision packed) ----------------
#define INS2(T0, T1, P) do { u64 _p = (P); \
    if (_p < T1) { if (_p < T0) { T1 = T0; T0 = _p; } else T1 = _p; } } while (0)

__launch_bounds__(256)
__global__ void mfma_argmin_kernel(const unsigned short* __restrict__ zh, const unsigned short* __restrict__ zl,
                                   const unsigned short* __restrict__ eh, const unsigned short* __restrict__ el,
                                   const float* __restrict__ ee, ulonglong2* __restrict__ top2) {
    __shared__ unsigned short Ah[2][128*32], Al[2][128*32], Bh[2][128*32], Bl[2][128*32]; // 64 KB
    __shared__ float eesh[K_];                                                           // 4 KB
    __shared__ u64 red[128][2][2];                                                       // 4 KB

    const int tid = threadIdx.x;
    const int lane = tid & 63, wave = tid >> 6;
    const int wr = wave >> 1, wc = wave & 1;
    const int row0 = blockIdx.x * 128;

    for (int i = tid; i < K_; i += 256) eesh[i] = ee[i];

    u64 t0[16], t1[16];
    #pragma unroll
    for (int s = 0; s < 16; ++s) { t0[s] = ~0ull; t1[s] = ~0ull; }

    // T2 swizzle: logical c-seg k of row r stored at phys seg k ^ ((r>>1)&3) (rule #21).
    const int lr  = lane >> 2;
    const int lc8 = (((lane & 3) ^ ((lr >> 1) & 3)) * 8);
    const int fr  = lane & 15;
    const int fk  = (((lane >> 4) ^ ((fr >> 1) & 3)) * 8);
    const int rb  = wave * 32;

#define STAGE(bf, step) do { int _kt = (step) >> 3, _c0 = ((step) & 7) * 32;            \
        size_t ga0 = (size_t)(row0 + rb + lr) * C_ + _c0 + lc8;                         \
        size_t ga1 = ga0 + (size_t)16 * C_;                                             \
        size_t gb0 = (size_t)(_kt * 128 + rb + lr) * C_ + _c0 + lc8;                    \
        size_t gb1 = gb0 + (size_t)16 * C_;                                             \
        GLD16(zh + ga0, &Ah[bf][(rb +  0) * 32]);                                       \
        GLD16(zh + ga1, &Ah[bf][(rb + 16) * 32]);                                       \
        GLD16(zl + ga0, &Al[bf][(rb +  0) * 32]);                                       \
        GLD16(zl + ga1, &Al[bf][(rb + 16) * 32]);                                       \
        GLD16(eh + gb0, &Bh[bf][(rb +  0) * 32]);                                       \
        GLD16(eh + gb1, &Bh[bf][(rb + 16) * 32]);                                       \
        GLD16(el + gb0, &Bl[bf][(rb +  0) * 32]);                                       \
        GLD16(el + gb1, &Bl[bf][(rb + 16) * 32]);                                       \
    } while (0)

    f32x4 acc[4][4];
    #pragma unroll
    for (int m = 0; m < 4; ++m)
        #pragma unroll
        for (int n = 0; n < 4; ++n) acc[m][n] = (f32x4){0.f, 0.f, 0.f, 0.f};

    STAGE(0, 0);
    __syncthreads();                       // stage-0 + eesh ready

    for (int s = 0; s < 64; ++s) {
        if (s < 63) STAGE((s + 1) & 1, s + 1);
        const int bf = s & 1;

        bf16x8 ah[4], al4[4], bh[4], bl4[4];
        #pragma unroll
        for (int m = 0; m < 4; ++m) {
            int r = wr * 64 + m * 16 + fr;
            ah[m]  = *(const bf16x8*)&Ah[bf][r * 32 + fk];
            al4[m] = *(const bf16x8*)&Al[bf][r * 32 + fk];
        }
        #pragma unroll
        for (int n = 0; n < 4; ++n) {
            int r = wc * 64 + n * 16 + fr;
            bh[n]  = *(const bf16x8*)&Bh[bf][r * 32 + fk];
            bl4[n] = *(const bf16x8*)&Bl[bf][r * 32 + fk];
        }
        #pragma unroll
        for (int m = 0; m < 4; ++m)
            #pragma unroll
            for (int n = 0; n < 4; ++n) {
                acc[m][n] = __builtin_amdgcn_mfma_f32_16x16x32_bf16(ah[m],  bh[n],  acc[m][n], 0, 0, 0);
                acc[m][n] = __builtin_amdgcn_mfma_f32_16x16x32_bf16(ah[m],  bl4[n], acc[m][n], 0, 0, 0);
                acc[m][n] = __builtin_amdgcn_mfma_f32_16x16x32_bf16(al4[m], bh[n],  acc[m][n], 0, 0, 0);
            }

        if ((s & 7) == 7) {                // kt-tile complete: fold into top-2, reset acc
            int kt = s >> 3;
            #pragma unroll
            for (int n = 0; n < 4; ++n) {
                int col = kt * 128 + wc * 64 + n * 16 + fr;
                float eev = eesh[col];
                #pragma unroll
                for (int m = 0; m < 4; ++m) {
                    #pragma unroll
                    for (int j = 0; j < 4; ++j) {
                        float d = eev - 2.0f * acc[m][n][j];
                        uint32_t bb = __float_as_uint(d);
                        uint32_t u = bb ^ (0x80000000u | (uint32_t)((int32_t)bb >> 31));
                        u64 p = ((u64)u << 10) | (uint32_t)col;
                        int sl = m * 4 + j;
                        INS2(t0[sl], t1[sl], p);
                    }
                }
            }
            #pragma unroll
            for (int m = 0; m < 4; ++m)
                #pragma unroll
                for (int n = 0; n < 4; ++n) acc[m][n] = (f32x4){0.f, 0.f, 0.f, 0.f};
        }
        __syncthreads();                   // vmcnt(0)+lgkmcnt(0)+barrier: next buf ready, cur reads done
    }

    // butterfly-merge top2 across the 16 lanes sharing each row
    #pragma unroll
    for (int st = 1; st < 16; st <<= 1) {
        #pragma unroll
        for (int s = 0; s < 16; ++s) {
            u64 q0 = shfl_xor64(t0[s], st);
            u64 q1 = shfl_xor64(t1[s], st);
            INS2(t0[s], t1[s], q0); INS2(t0[s], t1[s], q1);
        }
    }
    if ((lane & 15) == 0) {
        int g = lane >> 4;
        #pragma unroll
        for (int m = 0; m < 4; ++m)
            #pragma unroll
            for (int j = 0; j < 4; ++j) {
                int r = wr * 64 + m * 16 + g * 4 + j;
                int sl = m * 4 + j;
                red[r][wc][0] = t0[sl]; red[r][wc][1] = t1[sl];
            }
    }
    __syncthreads();
    if (tid < 128) {
        u64 a0 = red[tid][0][0], a1 = red[tid][0][1];
        u64 b0 = red[tid][1][0], b1 = red[tid][1][1];
        u64 o0, o1;
        if (a0 <= b0) { o0 = a0; o1 = (a1 < b0 ? a1 : b0); }
        else          { o0 = b0; o1 = (b1 < a0 ? b1 : a0); }
        top2[row0 + tid] = make_ulonglong2(o0, o1);
    }
#undef STAGE
}

// ---------------- triage: confident rows resolved; near-ties listed ----------------
__global__ void triage_kernel(const ulonglong2* __restrict__ top2,
                              int* __restrict__ idx_i, float* __restrict__ idx_f,
                              uint32_t* __restrict__ counter, uint32_t* __restrict__ needy) {
    int n = blockIdx.x * 256 + threadIdx.x;
    ulonglong2 t = top2[n];
    float d0 = unpack_d(t.x), d1 = unpack_d(t.y);
    if (d1 - d0 > GAP_THR) {
        int i0 = (int)(t.x & 0x3FFull);
        idx_i[n] = i0; idx_f[n] = (float)i0;
    } else {
        uint32_t p = atomicAdd(counter, 1u);
        needy[p] = (uint32_t)n;
    }
}

// ---------------- exact 2-candidate refine (verified fmaf chain + fused numpy-pairwise zz) ----------------
__launch_bounds__(256)
__global__ void exact2_kernel(const float* __restrict__ z, const float* __restrict__ emb,
                              const float* __restrict__ ee, const ulonglong2* __restrict__ top2,
                              const uint32_t* __restrict__ counter, const uint32_t* __restrict__ needy,
                              int* __restrict__ idx_i, float* __restrict__ idx_f) {
#pragma clang fp contract(off)
    uint32_t cnt = *counter;
    for (uint32_t g = blockIdx.x * 256 + threadIdx.x; g < cnt; g += gridDim.x * 256) {
        int n = (int)needy[g];
        int b = n >> 12, hw = n & 4095;
        ulonglong2 tt = top2[n];
        int c0 = (int)(tt.x & 0x3FFull);
        int c1 = (int)(tt.y & 0x3FFull);
        if (c1 < c0) { int t = c0; c0 = c1; c1 = t; }
        const float* zp = z + (size_t)b * C_ * HW_ + hw;
        const float4* e0 = (const float4*)(emb + (size_t)c0 * C_);
        const float4* e1 = (const float4*)(emb + (size_t)c1 * C_);
        float a0 = 0.f, a1 = 0.f;
        float zzr = 0.f;
        #pragma unroll
        for (int half = 0; half < 2; ++half) {
            float r[8];
            #pragma unroll 2
            for (int c4l = 0; c4l < 2; ++c4l) {
                int c4 = half * 32 + c4l;
                float4 v0 = e0[c4], v1 = e1[c4];
                #pragma unroll
                for (int i = 0; i < 4; ++i) {
                    int c = c4 * 4 + i;
                    float zv = zp[(size_t)c * HW_];
                    r[c4l * 4 + i] = zv * zv;
                    a0 = fmaf(zv, ((const float*)&v0)[i], a0);
                    a1 = fmaf(zv, ((const float*)&v1)[i], a1);
                }
            }
            #pragma unroll 6
            for (int c4l = 2; c4l < 32; ++c4l) {
                int c4 = half * 32 + c4l;
                float4 v0 = e0[c4], v1 = e1[c4];
                #pragma unroll
                for (int i = 0; i < 4; ++i) {
                    int c = c4 * 4 + i;
                    float zv = zp[(size_t)c * HW_];
                    float sq = zv * zv;
                    int j = (c4l * 4 + i) & 7;
                    r[j] = r[j] + sq;
                    a0 = fmaf(zv, ((const float*)&v0)[i], a0);
                    a1 = fmaf(zv, ((const float*)&v1)[i], a1);
                }
            }
            float s = ((r[0] + r[1]) + (r[2] + r[3])) + ((r[4] + r[5]) + (r[6] + r[7]));
            zzr = zzr + s;
        }
        float A0 = zzr + ee[c0]; float d0 = A0 - 2.0f * a0;
        float A1 = zzr + ee[c1]; float d1 = A1 - 2.0f * a1;
        int bi = c0;
        if (d1 < d0) bi = c1;
        idx_i[n] = bi;
        idx_f[n] = (float)bi;
    }
}

// ---------------- gather zq_st (straight-through) + loss partials ----------------
__global__ void gather_kernel(const float* __restrict__ z, const float* __restrict__ emb,
                              const int* __restrict__ idx, float* __restrict__ zq,
                              float* __restrict__ partials) {
#pragma clang fp contract(off)
    const long long TOT = (long long)N_ * (C_/4);
    float ls = 0.f;
    for (long long g = (long long)blockIdx.x * blockDim.x + threadIdx.x; g < TOT;
         g += (long long)gridDim.x * blockDim.x) {
        int c4 = (int)(g >> 17);
        int n  = (int)(g & (N_ - 1));
        int b = n >> 12, hw = n & 4095;
        int j = idx[n];
        float4 e4 = *(const float4*)&emb[(size_t)j * C_ + c4*4];
        size_t base = (size_t)b * C_ * HW_ + (size_t)(c4*4) * HW_ + hw;
        float zv, df;
        zv = z[base + 0*HW_]; df = e4.x - zv; zq[base + 0*HW_] = zv + df; ls += df*df;
        zv = z[base + 1*HW_]; df = e4.y - zv; zq[base + 1*HW_] = zv + df; ls += df*df;
        zv = z[base + 2*HW_]; df = e4.z - zv; zq[base + 2*HW_] = zv + df; ls += df*df;
        zv = z[base + 3*HW_]; df = e4.w - zv; zq[base + 3*HW_] = zv + df; ls += df*df;
    }
    __shared__ float sred[256];
    sred[threadIdx.x] = ls;
    __syncthreads();
    for (int s = 128; s > 0; s >>= 1) {
        if (threadIdx.x < s) sred[threadIdx.x] += sred[threadIdx.x + s];
        __syncthreads();
    }
    if (threadIdx.x == 0) partials[blockIdx.x] = sred[0];
}

__global__ void finalize_kernel(const float* __restrict__ partials, int nparts,
                                float* __restrict__ loss_out) {
    __shared__ float sred[256];
    float s = 0.f;
    for (int i = threadIdx.x; i < nparts; i += 256) s += partials[i];
    sred[threadIdx.x] = s; __syncthreads();
    for (int st = 128; st > 0; st >>= 1) {
        if (threadIdx.x < st) sred[threadIdx.x] += sred[threadIdx.x + st];
        __syncthreads();
    }
    if (threadIdx.x == 0) {
        float m = sred[0] / 33554432.0f;
        *loss_out = m - 0.25f * m;
    }
}

extern "C" void kernel_launch(void* const* d_in, const int* in_sizes, int n_in,
                              void* d_out, int out_size, void* d_ws, size_t ws_size,
                              hipStream_t stream) {
    const float* z   = (const float*)d_in[0];
    const float* emb = (const float*)d_in[1];
    float* out   = (float*)d_out;
    float* zq    = out;                        // 33554432 floats
    float* idx_f = out + (size_t)N_ * C_;      // 131072
    float* loss  = idx_f + N_;                 // 1

    // zh/zl (bf16, [n][c]) live in the zq region (exactly 134 MB); gather overwrites later.
    unsigned short* zh = (unsigned short*)d_out;
    unsigned short* zl = zh + (size_t)N_ * C_;

    float*      ee       = (float*)d_ws;                       // 1024 f
    int*        idx_i    = (int*)(ee + K_);                    // 131072 i32
    ulonglong2* top2     = (ulonglong2*)(idx_i + N_);          // 131072 x 16B = 2 MB
    float*      partials = (float*)(top2 + N_);                // 2048 f
    uint32_t*   counter  = (uint32_t*)(partials + 2048);       // 16 B slot
    unsigned short* eh   = (unsigned short*)(counter + 4);     // 262144 ushort
    unsigned short* el   = eh + (size_t)K_ * C_;               // 262144 ushort
    uint32_t*   needy    = (uint32_t*)el;                      // aliases el (dead after argmin)

    hipMemsetAsync(counter, 0, 4, stream);
    esplit_kernel<<<128, 256, 0, stream>>>(emb, eh, el);
    ee_kernel<<<(K_ + 255)/256, 256, 0, stream>>>(emb, ee);
    zsplit_kernel<<<8192, 256, 0, stream>>>(z, zh, zl);
    mfma_argmin_kernel<<<N_/128, 256, 0, stream>>>(zh, zl, eh, el, ee, top2);
    triage_kernel<<<N_/256, 256, 0, stream>>>(top2, idx_i, idx_f, counter, needy);
    exact2_kernel<<<64, 256, 0, stream>>>(z, emb, ee, top2, counter, needy, idx_i, idx_f);
    gather_kernel<<<2048, 256, 0, stream>>>(z, emb, idx_i, zq, partials);
    finalize_kernel<<<1, 256, 0, stream>>>(partials, 2048, loss);
}